// Round 3
// baseline (1100.159 us; speedup 1.0000x reference)
//
#include <hip/hip_runtime.h>
#include <math.h>

// Problem: B=16, M=1024, N=1024 fp32; 20 ADMM iterations.
// RHO=1, LAMBD=0.1, ALPHA=0.5 -> threshold = 0.05, scale-const = 0.05.
//
// Fused persistent kernel (plain launch + 2-level grid barrier), with a
// host-side occupancy gate and a verbatim fallback to the proven
// multi-kernel version if co-residency cannot be guaranteed.
//
// State collapse: V_t = R_t + Z_{t-1} is the ONLY per-element state (VGPRs).
//   X_t = sc_t * softthr(V_t);  Z_t = V_t - X_t
//   R_{t+1} = normalize(sqrt(R0') * sqrt(X_t') * exp(-Z_t/2))
//   V_{t+1} = R_{t+1} + Z_t
// V >= 0 provably holds every iteration, so softthr(x) = fmaxf(x-THR, 0).
//
// R3 changes vs R2 (which was stall-bound: VALU 9%, HBM 4%):
//  - barrier: distributed arrival (64 counters, 64B apart, 16 arrivals each)
//    + single release word published by block 0. Read-only release polling;
//    no RMW/poll interference on one line.
//  - phase-0 colsum readback: plain float4 loads again (L2-allocating).
//    Safe: kernel-start acquire invalidated L2; device-scope atomics update
//    the coherence point and don't allocate into local L2; first local touch
//    of cs[t-1] happens only after its last write.
#define NN 1024
#define NROWS 16384
#define TPB 256           // 4 waves/block
#define WPB 4
#define KSLOT 16
#define NIT 20

// fused config: 4 rows/wave -> 16 rows/block -> 1024 blocks (4/CU)
#define F_RPW 4
#define F_RPB (WPB * F_RPW)
#define F_NGRID (NROWS / F_RPB)   // 1024

// fallback config (proven): 2 rows/wave -> 8 rows/block -> 2048 blocks
#define FB_RPW 2
#define FB_RPB (WPB * FB_RPW)
#define FB_NGRID (NROWS / FB_RPB) // 2048

#define MINV 1e-40f
#define THR  0.05f   // ALPHA*LAMBD/RHO
#define SCLC 0.05f   // (1-ALPHA)*LAMBD/RHO
#define EPSL 1e-10f

#define CS_BYTES ((size_t)NIT * KSLOT * NN * sizeof(float))
#define NARR 64                   // arrival counters
#define ARR_STRIDE 16             // u32s -> 64 B apart
#define BLKS_PER_ARR (F_NGRID / NARR)  // 16

__device__ __forceinline__ float wred_sum(float v) {
#pragma unroll
  for (int o = 32; o > 0; o >>= 1) v += __shfl_xor(v, o, 64);
  return v;
}
__device__ __forceinline__ float softthr_full(float x) {
  return copysignf(fmaxf(fabsf(x) - THR, 0.0f), x);
}

// Two-level grid barrier, generation g = 1,2,3,...
// arr: NARR counters spread 64 B apart; rel: single release word.
__device__ __forceinline__ void gbar2(unsigned* __restrict__ arr,
                                      unsigned* __restrict__ rel, unsigned g) {
  __syncthreads();
  if (threadIdx.x == 0) {
    __threadfence();  // release my block's cs atomics
    __hip_atomic_fetch_add(&arr[(blockIdx.x & (NARR - 1)) * ARR_STRIDE], 1u,
                           __ATOMIC_RELEASE, __HIP_MEMORY_SCOPE_AGENT);
  }
  if (blockIdx.x == 0) {
    // wave 0 aggregates the 64 arrival counters
    if (threadIdx.x < NARR) {
      const unsigned tgt = (unsigned)BLKS_PER_ARR * g;
      while (__hip_atomic_load(&arr[threadIdx.x * ARR_STRIDE], __ATOMIC_RELAXED,
                               __HIP_MEMORY_SCOPE_AGENT) < tgt)
        __builtin_amdgcn_s_sleep(1);
    }
    __syncthreads();
    if (threadIdx.x == 0) {
      __threadfence();
      __hip_atomic_store(rel, g, __ATOMIC_RELEASE, __HIP_MEMORY_SCOPE_AGENT);
    }
  } else {
    if (threadIdx.x == 0) {
      while (__hip_atomic_load(rel, __ATOMIC_RELAXED,
                               __HIP_MEMORY_SCOPE_AGENT) < g)
        __builtin_amdgcn_s_sleep(2);
      __threadfence();  // acquire side
    }
    __syncthreads();
  }
}

// ============================ fused kernel =================================
// Layout: row = blockIdx.x*16 + wave*4 + rr; lane L covers cols {c*256+L*4+j}.
__global__ __launch_bounds__(TPB, 4) void k_fused(const float* __restrict__ R0,
                                                  float* __restrict__ OUT,
                                                  float* __restrict__ SQ,
                                                  float* __restrict__ cs,
                                                  unsigned* __restrict__ arr,
                                                  unsigned* __restrict__ rel) {
  __shared__ float s_scale[NN];       // 4 KB
  __shared__ float s_part[WPB * NN];  // 16 KB  (20 KB total -> 4 blocks/CU)
  const int lane = threadIdx.x & 63;
  const int wv = threadIdx.x >> 6;
  const size_t row0 = (size_t)blockIdx.x * F_RPB + (size_t)wv * F_RPW;

  float V[F_RPW][16];  // persistent per-thread state (64 VGPRs)

  // ---- iter 0: V_1 = R0'/rowsum(R0'); SQ = sqrt(R0'); cs[0] += softthr^2.
#pragma unroll
  for (int rr = 0; rr < F_RPW; ++rr) {
    const size_t base = (row0 + rr) * NN + (size_t)lane * 4;
    float sloc = 0.f;
#pragma unroll
    for (int c = 0; c < 4; ++c) {
      const float4 r4 = *(const float4*)(R0 + base + c * 256);
      float* p = &V[rr][c * 4];
      p[0] = (r4.x == 0.f) ? MINV : r4.x;
      p[1] = (r4.y == 0.f) ? MINV : r4.y;
      p[2] = (r4.z == 0.f) ? MINV : r4.z;
      p[3] = (r4.w == 0.f) ? MINV : r4.w;
      sloc += (p[0] + p[1]) + (p[2] + p[3]);
      *(float4*)(SQ + base + c * 256) =
          make_float4(sqrtf(p[0]), sqrtf(p[1]), sqrtf(p[2]), sqrtf(p[3]));
    }
    const float inv = 1.0f / wred_sum(sloc);
#pragma unroll
    for (int c = 0; c < 4; ++c) {
      float a[4];
#pragma unroll
      for (int j = 0; j < 4; ++j) {
        const float rn = V[rr][c * 4 + j] * inv;  // V_1 = R_1 (Z_0 = 0)
        V[rr][c * 4 + j] = rn;
        const float s = fmaxf(rn - THR, 0.f);     // V >= 0
        a[j] = s * s;
      }
      float* sp = &s_part[wv * NN + c * 256 + lane * 4];
      if (rr == 0) {
        *(float4*)sp = make_float4(a[0], a[1], a[2], a[3]);
      } else {
        float4 o = *(float4*)sp;
        *(float4*)sp = make_float4(o.x + a[0], o.y + a[1], o.z + a[2], o.w + a[3]);
      }
    }
  }
  __syncthreads();
  {
    const int col = threadIdx.x * 4;
    const float4 s0 = *(float4*)(&s_part[0 * NN + col]);
    const float4 s1 = *(float4*)(&s_part[1 * NN + col]);
    const float4 s2 = *(float4*)(&s_part[2 * NN + col]);
    const float4 s3 = *(float4*)(&s_part[3 * NN + col]);
    float* dst = cs + (size_t)(blockIdx.x & (KSLOT - 1)) * NN + col;
    atomicAdd(dst + 0, (s0.x + s1.x) + (s2.x + s3.x));
    atomicAdd(dst + 1, (s0.y + s1.y) + (s2.y + s3.y));
    atomicAdd(dst + 2, (s0.z + s1.z) + (s2.z + s3.z));
    atomicAdd(dst + 3, (s0.w + s1.w) + (s2.w + s3.w));
  }
  gbar2(arr, rel, 1u);

  // ---- iters t=1..19
#pragma unroll 1
  for (int t = 1; t < NIT; ++t) {
    const int last = (t == NIT - 1) ? 1 : 0;
    const float* csP = cs + (size_t)(t - 1) * KSLOT * NN;
    float* csN = cs + (size_t)t * KSLOT * NN;

    // Phase 0: scale[col] = max(1 - SCLC/(sqrt(sum_k cs[k][col]) + EPS), 0)
    {
      const int col = threadIdx.x * 4;
      float4 a = make_float4(0.f, 0.f, 0.f, 0.f);
#pragma unroll
      for (int k = 0; k < KSLOT; ++k) {
        const float4 v = *(const float4*)(csP + (size_t)k * NN + col);
        a.x += v.x; a.y += v.y; a.z += v.z; a.w += v.w;
      }
      s_scale[col + 0] = fmaxf(1.0f - SCLC / (sqrtf(a.x) + EPSL), 0.0f);
      s_scale[col + 1] = fmaxf(1.0f - SCLC / (sqrtf(a.y) + EPSL), 0.0f);
      s_scale[col + 2] = fmaxf(1.0f - SCLC / (sqrtf(a.z) + EPSL), 0.0f);
      s_scale[col + 3] = fmaxf(1.0f - SCLC / (sqrtf(a.w) + EPSL), 0.0f);
    }
    __syncthreads();

#pragma unroll
    for (int rr = 0; rr < F_RPW; ++rr) {
      const size_t base = (row0 + rr) * NN + (size_t)lane * 4;
      float u[16];
      float sloc = 0.f;
#pragma unroll
      for (int c = 0; c < 4; ++c) {
        const float4 sq4 = *(const float4*)(SQ + base + c * 256);
        const float4 sc4 = *(const float4*)(&s_scale[c * 256 + lane * 4]);
        const float sq[4] = {sq4.x, sq4.y, sq4.z, sq4.w};
        const float sc[4] = {sc4.x, sc4.y, sc4.z, sc4.w};
#pragma unroll
        for (int j = 0; j < 4; ++j) {
          const float vv = V[rr][c * 4 + j];
          const float s = fmaxf(vv - THR, 0.f);   // softthr, V>=0
          const float X = sc[j] * s;              // X_t (never stored)
          const float zz = vv - X;                // Z_t
          const float Xm = (X == 0.f) ? MINV : X;
          const float uu = sq[j] * sqrtf(Xm) * __expf(-0.5f * zz);
          u[c * 4 + j] = uu;
          V[rr][c * 4 + j] = zz;                  // state slot now holds z
          sloc += uu;
        }
      }
      const float inv = 1.0f / wred_sum(sloc);
      if (!last) {
#pragma unroll
        for (int c = 0; c < 4; ++c) {
          float a[4];
#pragma unroll
          for (int j = 0; j < 4; ++j) {
            const float nv = u[c * 4 + j] * inv + V[rr][c * 4 + j];  // R+z
            V[rr][c * 4 + j] = nv;               // V_{t+1}
            const float s = fmaxf(nv - THR, 0.f);
            a[j] = s * s;
          }
          float* sp = &s_part[wv * NN + c * 256 + lane * 4];
          if (rr == 0) {
            *(float4*)sp = make_float4(a[0], a[1], a[2], a[3]);
          } else {
            float4 o = *(float4*)sp;
            *(float4*)sp =
                make_float4(o.x + a[0], o.y + a[1], o.z + a[2], o.w + a[3]);
          }
        }
      } else {
#pragma unroll
        for (int c = 0; c < 4; ++c) {
          *(float4*)(OUT + base + c * 256) =
              make_float4(u[c * 4 + 0] * inv, u[c * 4 + 1] * inv,
                          u[c * 4 + 2] * inv, u[c * 4 + 3] * inv);  // R_20
        }
      }
    }

    if (!last) {
      __syncthreads();
      {
        const int col = threadIdx.x * 4;
        const float4 s0 = *(float4*)(&s_part[0 * NN + col]);
        const float4 s1 = *(float4*)(&s_part[1 * NN + col]);
        const float4 s2 = *(float4*)(&s_part[2 * NN + col]);
        const float4 s3 = *(float4*)(&s_part[3 * NN + col]);
        float* dst = csN + (size_t)(blockIdx.x & (KSLOT - 1)) * NN + col;
        atomicAdd(dst + 0, (s0.x + s1.x) + (s2.x + s3.x));
        atomicAdd(dst + 1, (s0.y + s1.y) + (s2.y + s3.y));
        atomicAdd(dst + 2, (s0.z + s1.z) + (s2.z + s3.z));
        atomicAdd(dst + 3, (s0.w + s1.w) + (s2.w + s3.w));
      }
      gbar2(arr, rel, (unsigned)(t + 1));
    }
  }
}

// ======================= fallback (proven, 1108 µs) ========================
__global__ __launch_bounds__(TPB) void k_start(const float* __restrict__ R0,
                                               float* __restrict__ V,
                                               float* __restrict__ SQ,
                                               float* __restrict__ cs0) {
  __shared__ float s_part[WPB * NN];
  const int lane = threadIdx.x & 63;
  const int wv = threadIdx.x >> 6;
#pragma unroll
  for (int rr = 0; rr < FB_RPW; ++rr) {
    const size_t row = (size_t)blockIdx.x * FB_RPB + wv * FB_RPW + rr;
    const size_t base = row * NN + (size_t)lane * 4;
    float r0v[16];
    float sloc = 0.f;
#pragma unroll
    for (int c = 0; c < 4; ++c) {
      const float4 r4 = *(const float4*)(R0 + base + c * 256);
      float* p = &r0v[c * 4];
      p[0] = (r4.x == 0.f) ? MINV : r4.x;
      p[1] = (r4.y == 0.f) ? MINV : r4.y;
      p[2] = (r4.z == 0.f) ? MINV : r4.z;
      p[3] = (r4.w == 0.f) ? MINV : r4.w;
      sloc += (p[0] + p[1]) + (p[2] + p[3]);
      *(float4*)(SQ + base + c * 256) =
          make_float4(sqrtf(p[0]), sqrtf(p[1]), sqrtf(p[2]), sqrtf(p[3]));
    }
    const float inv = 1.0f / wred_sum(sloc);
#pragma unroll
    for (int c = 0; c < 4; ++c) {
      float rn[4], a[4];
#pragma unroll
      for (int j = 0; j < 4; ++j) {
        rn[j] = r0v[c * 4 + j] * inv;
        const float s = softthr_full(rn[j]);
        a[j] = s * s;
      }
      *(float4*)(V + base + c * 256) = make_float4(rn[0], rn[1], rn[2], rn[3]);
      float* sp = &s_part[wv * NN + c * 256 + lane * 4];
      if (rr == 0) {
        *(float4*)sp = make_float4(a[0], a[1], a[2], a[3]);
      } else {
        float4 o = *(float4*)sp;
        *(float4*)sp = make_float4(o.x + a[0], o.y + a[1], o.z + a[2], o.w + a[3]);
      }
    }
  }
  __syncthreads();
  const int col = threadIdx.x * 4;
  const float4 s0 = *(float4*)(&s_part[0 * NN + col]);
  const float4 s1 = *(float4*)(&s_part[1 * NN + col]);
  const float4 s2 = *(float4*)(&s_part[2 * NN + col]);
  const float4 s3 = *(float4*)(&s_part[3 * NN + col]);
  float* dst = cs0 + (size_t)(blockIdx.x & (KSLOT - 1)) * NN + col;
  atomicAdd(dst + 0, (s0.x + s1.x) + (s2.x + s3.x));
  atomicAdd(dst + 1, (s0.y + s1.y) + (s2.y + s3.y));
  atomicAdd(dst + 2, (s0.z + s1.z) + (s2.z + s3.z));
  atomicAdd(dst + 3, (s0.w + s1.w) + (s2.w + s3.w));
}

__global__ __launch_bounds__(TPB) void k_ab(float* __restrict__ V,
                                            const float* __restrict__ SQ,
                                            const float* __restrict__ csPrev,
                                            float* __restrict__ csNext,
                                            int last) {
  __shared__ float s_scale[NN];
  __shared__ float s_part[WPB * NN];
  const int lane = threadIdx.x & 63;
  const int wv = threadIdx.x >> 6;
  {
    const int col = threadIdx.x * 4;
    float4 a = make_float4(0.f, 0.f, 0.f, 0.f);
#pragma unroll
    for (int k = 0; k < KSLOT; ++k) {
      const float4 v = *(const float4*)(csPrev + (size_t)k * NN + col);
      a.x += v.x; a.y += v.y; a.z += v.z; a.w += v.w;
    }
    s_scale[col + 0] = fmaxf(1.0f - SCLC / (sqrtf(a.x) + EPSL), 0.0f);
    s_scale[col + 1] = fmaxf(1.0f - SCLC / (sqrtf(a.y) + EPSL), 0.0f);
    s_scale[col + 2] = fmaxf(1.0f - SCLC / (sqrtf(a.z) + EPSL), 0.0f);
    s_scale[col + 3] = fmaxf(1.0f - SCLC / (sqrtf(a.w) + EPSL), 0.0f);
  }
  __syncthreads();

#pragma unroll
  for (int rr = 0; rr < FB_RPW; ++rr) {
    const size_t row = (size_t)blockIdx.x * FB_RPB + wv * FB_RPW + rr;
    const size_t base = row * NN + (size_t)lane * 4;
    float u[16], z[16];
    float sloc = 0.f;
#pragma unroll
    for (int c = 0; c < 4; ++c) {
      const float4 vv4 = *(const float4*)(V + base + c * 256);
      const float4 sq4 = *(const float4*)(SQ + base + c * 256);
      const float4 sc4 = *(const float4*)(&s_scale[c * 256 + lane * 4]);
      const float vv[4] = {vv4.x, vv4.y, vv4.z, vv4.w};
      const float sq[4] = {sq4.x, sq4.y, sq4.z, sq4.w};
      const float sc[4] = {sc4.x, sc4.y, sc4.z, sc4.w};
#pragma unroll
      for (int j = 0; j < 4; ++j) {
        const float s = softthr_full(vv[j]);
        const float X = sc[j] * s;
        const float zz = vv[j] - X;
        z[c * 4 + j] = zz;
        const float Xm = (X == 0.f) ? MINV : X;
        const float uu = sq[j] * sqrtf(Xm) * __expf(-0.5f * zz);
        u[c * 4 + j] = uu;
        sloc += uu;
      }
    }
    const float inv = 1.0f / wred_sum(sloc);
#pragma unroll
    for (int c = 0; c < 4; ++c) {
      float outv[4];
#pragma unroll
      for (int j = 0; j < 4; ++j) {
        const float rn = u[c * 4 + j] * inv;
        outv[j] = last ? rn : (rn + z[c * 4 + j]);
      }
      *(float4*)(V + base + c * 256) =
          make_float4(outv[0], outv[1], outv[2], outv[3]);
      if (!last) {
        float a[4];
#pragma unroll
        for (int j = 0; j < 4; ++j) {
          const float s = softthr_full(outv[j]);
          a[j] = s * s;
        }
        float* sp = &s_part[wv * NN + c * 256 + lane * 4];
        if (rr == 0) {
          *(float4*)sp = make_float4(a[0], a[1], a[2], a[3]);
        } else {
          float4 o = *(float4*)sp;
          *(float4*)sp =
              make_float4(o.x + a[0], o.y + a[1], o.z + a[2], o.w + a[3]);
        }
      }
    }
  }
  if (!last) {
    __syncthreads();
    const int col = threadIdx.x * 4;
    const float4 s0 = *(float4*)(&s_part[0 * NN + col]);
    const float4 s1 = *(float4*)(&s_part[1 * NN + col]);
    const float4 s2 = *(float4*)(&s_part[2 * NN + col]);
    const float4 s3 = *(float4*)(&s_part[3 * NN + col]);
    float* dst = csNext + (size_t)(blockIdx.x & (KSLOT - 1)) * NN + col;
    atomicAdd(dst + 0, (s0.x + s1.x) + (s2.x + s3.x));
    atomicAdd(dst + 1, (s0.y + s1.y) + (s2.y + s3.y));
    atomicAdd(dst + 2, (s0.z + s1.z) + (s2.z + s3.z));
    atomicAdd(dst + 3, (s0.w + s1.w) + (s2.w + s3.w));
  }
}

extern "C" void kernel_launch(void* const* d_in, const int* in_sizes, int n_in,
                              void* d_out, int out_size, void* d_ws, size_t ws_size,
                              hipStream_t stream) {
  (void)in_sizes; (void)n_in; (void)out_size; (void)ws_size;
  const float* R0 = (const float*)d_in[0];
  float* OUT = (float*)d_out;
  float* SQ = (float*)d_ws;   // 64 MB: sqrt(R0'), iteration-invariant
  float* cs = (float*)((char*)d_ws + (size_t)NROWS * NN * sizeof(float));
  unsigned* arr = (unsigned*)((char*)cs + CS_BYTES);       // 4 KB counters
  unsigned* rel = arr + NARR * ARR_STRIDE + 64;            // own cacheline

  // Co-residency gate: fused persistent kernel only if all 1024 blocks fit.
  static int mode = -1;
  if (mode < 0) {
    mode = 0;
    int dev = 0, ncu = 0, maxb = 0;
    if (hipGetDevice(&dev) == hipSuccess &&
        hipDeviceGetAttribute(&ncu, hipDeviceAttributeMultiprocessorCount,
                              dev) == hipSuccess &&
        hipOccupancyMaxActiveBlocksPerMultiprocessor(&maxb, k_fused, TPB, 0) ==
            hipSuccess) {
      if ((long)maxb * (long)ncu >= (long)F_NGRID) mode = 1;
    }
  }

  // zero cs slices + arrival counters + release word
  hipMemsetAsync(cs, 0, CS_BYTES + 8192, stream);
  if (mode == 1) {
    k_fused<<<F_NGRID, TPB, 0, stream>>>(R0, OUT, SQ, cs, arr, rel);
  } else {
    k_start<<<FB_NGRID, TPB, 0, stream>>>(R0, OUT, SQ, cs);
    for (int it = 1; it < NIT; ++it) {
      k_ab<<<FB_NGRID, TPB, 0, stream>>>(OUT, SQ,
                                         cs + (size_t)(it - 1) * KSLOT * NN,
                                         cs + (size_t)it * KSLOT * NN,
                                         (it == NIT - 1) ? 1 : 0);
    }
  }
}

// Round 4
// 1027.229 us; speedup vs baseline: 1.0710x; 1.0710x over previous
//
#include <hip/hip_runtime.h>
#include <math.h>

// Problem: B=16, M=1024, N=1024 fp32; 20 ADMM iterations.
// RHO=1, LAMBD=0.1, ALPHA=0.5 -> threshold = 0.05, scale-const = 0.05.
//
// Fused persistent kernel, V in VGPRs for real this time.
//
// R4 root-cause fix: R2/R3 used __launch_bounds__(256,4) -> VGPR cap 128,
// but V[4][16]+u+temps needs ~170 -> compiler spilled V to SCRATCH
// (rocprof: VGPR_Count=64, WRITE_SIZE 464MB = scratch writeback). Fused ==
// fallback time because V still streamed through memory every iteration.
// Register math: state/lane = 256/w floats, VGPR cap = 512/w (w waves/SIMD).
//   w=4: 64 state, 64 headroom -> spilled.  w=2: 128 state, 128 headroom OK.
// => 512 blocks x 256 thr, RPW=8, __launch_bounds__(256,2) (cap 256 VGPR).
// Co-residency guaranteed: VGPR<=256 -> 2 waves/SIMD -> 2 blocks/CU;
// LDS 20KB -> 8/CU; 2 x 256 CUs = 512 blocks. No occupancy-API gate needed.
//
//   X_t = sc_t * softthr(V_t);  Z_t = V_t - X_t
//   R_{t+1} = normalize(sqrt(R0') * sqrt(X_t') * exp(-Z_t/2))
//   V_{t+1} = R_{t+1} + Z_t
// V >= 0 provably holds every iteration, so softthr(x) = fmaxf(x-THR, 0).
#define NN 1024
#define NROWS 16384
#define TPB 256           // 4 waves/block
#define WPB 4
#define KSLOT 16
#define NIT 20

// fused config: 8 rows/wave -> 32 rows/block -> 512 blocks (2/CU)
#define F_RPW 8
#define F_RPB (WPB * F_RPW)
#define F_NGRID (NROWS / F_RPB)   // 512

// fallback config (proven): 2 rows/wave -> 8 rows/block -> 2048 blocks
#define FB_RPW 2
#define FB_RPB (WPB * FB_RPW)
#define FB_NGRID (NROWS / FB_RPB) // 2048

#define MINV 1e-40f
#define THR  0.05f   // ALPHA*LAMBD/RHO
#define SCLC 0.05f   // (1-ALPHA)*LAMBD/RHO
#define EPSL 1e-10f

#define CS_BYTES ((size_t)NIT * KSLOT * NN * sizeof(float))
#define NARR 64                   // arrival counters
#define ARR_STRIDE 16             // u32s -> 64 B apart
#define BLKS_PER_ARR (F_NGRID / NARR)  // 8

__device__ __forceinline__ float wred_sum(float v) {
#pragma unroll
  for (int o = 32; o > 0; o >>= 1) v += __shfl_xor(v, o, 64);
  return v;
}
__device__ __forceinline__ float softthr_full(float x) {
  return copysignf(fmaxf(fabsf(x) - THR, 0.0f), x);
}

// Two-level grid barrier, generation g = 1,2,3,...
__device__ __forceinline__ void gbar2(unsigned* __restrict__ arr,
                                      unsigned* __restrict__ rel, unsigned g) {
  __syncthreads();
  if (threadIdx.x == 0) {
    __threadfence();  // release my block's cs atomics
    __hip_atomic_fetch_add(&arr[(blockIdx.x & (NARR - 1)) * ARR_STRIDE], 1u,
                           __ATOMIC_RELEASE, __HIP_MEMORY_SCOPE_AGENT);
  }
  if (blockIdx.x == 0) {
    if (threadIdx.x < NARR) {
      const unsigned tgt = (unsigned)BLKS_PER_ARR * g;
      while (__hip_atomic_load(&arr[threadIdx.x * ARR_STRIDE], __ATOMIC_RELAXED,
                               __HIP_MEMORY_SCOPE_AGENT) < tgt)
        __builtin_amdgcn_s_sleep(1);
    }
    __syncthreads();
    if (threadIdx.x == 0) {
      __threadfence();
      __hip_atomic_store(rel, g, __ATOMIC_RELEASE, __HIP_MEMORY_SCOPE_AGENT);
    }
  } else {
    if (threadIdx.x == 0) {
      while (__hip_atomic_load(rel, __ATOMIC_RELAXED,
                               __HIP_MEMORY_SCOPE_AGENT) < g)
        __builtin_amdgcn_s_sleep(2);
      __threadfence();  // acquire side
    }
    __syncthreads();
  }
}

// ============================ fused kernel =================================
// Layout: row = blockIdx.x*32 + wave*8 + rr; lane L covers cols {c*256+L*4+j}.
// All global accesses are coalesced float4. All V/u indices compile-time.
__global__ __launch_bounds__(TPB, 2) void k_fused(const float* __restrict__ R0,
                                                  float* __restrict__ OUT,
                                                  float* __restrict__ SQ,
                                                  float* __restrict__ cs,
                                                  unsigned* __restrict__ arr,
                                                  unsigned* __restrict__ rel) {
  __shared__ float s_scale[NN];       // 4 KB
  __shared__ float s_part[WPB * NN];  // 16 KB  (20 KB total)
  const int lane = threadIdx.x & 63;
  const int wv = threadIdx.x >> 6;
  const size_t row0 = (size_t)blockIdx.x * F_RPB + (size_t)wv * F_RPW;

  float V[F_RPW][16];  // persistent per-thread state (128 VGPRs)

  // ---- iter 0: V_1 = R0'/rowsum(R0'); SQ = sqrt(R0'); cs[0] += softthr^2.
#pragma unroll
  for (int rr = 0; rr < F_RPW; ++rr) {
    const size_t base = (row0 + rr) * NN + (size_t)lane * 4;
    float sloc = 0.f;
#pragma unroll
    for (int c = 0; c < 4; ++c) {
      const float4 r4 = *(const float4*)(R0 + base + c * 256);
      const float p0 = (r4.x == 0.f) ? MINV : r4.x;
      const float p1 = (r4.y == 0.f) ? MINV : r4.y;
      const float p2 = (r4.z == 0.f) ? MINV : r4.z;
      const float p3 = (r4.w == 0.f) ? MINV : r4.w;
      V[rr][c * 4 + 0] = p0;
      V[rr][c * 4 + 1] = p1;
      V[rr][c * 4 + 2] = p2;
      V[rr][c * 4 + 3] = p3;
      sloc += (p0 + p1) + (p2 + p3);
      *(float4*)(SQ + base + c * 256) =
          make_float4(sqrtf(p0), sqrtf(p1), sqrtf(p2), sqrtf(p3));
    }
    const float inv = 1.0f / wred_sum(sloc);
#pragma unroll
    for (int c = 0; c < 4; ++c) {
      float a[4];
#pragma unroll
      for (int j = 0; j < 4; ++j) {
        const float rn = V[rr][c * 4 + j] * inv;  // V_1 = R_1 (Z_0 = 0)
        V[rr][c * 4 + j] = rn;
        const float s = fmaxf(rn - THR, 0.f);     // V >= 0
        a[j] = s * s;
      }
      float* sp = &s_part[wv * NN + c * 256 + lane * 4];
      if (rr == 0) {
        *(float4*)sp = make_float4(a[0], a[1], a[2], a[3]);
      } else {
        float4 o = *(float4*)sp;
        *(float4*)sp = make_float4(o.x + a[0], o.y + a[1], o.z + a[2], o.w + a[3]);
      }
    }
  }
  __syncthreads();
  {
    const int col = threadIdx.x * 4;
    const float4 s0 = *(float4*)(&s_part[0 * NN + col]);
    const float4 s1 = *(float4*)(&s_part[1 * NN + col]);
    const float4 s2 = *(float4*)(&s_part[2 * NN + col]);
    const float4 s3 = *(float4*)(&s_part[3 * NN + col]);
    float* dst = cs + (size_t)(blockIdx.x & (KSLOT - 1)) * NN + col;
    atomicAdd(dst + 0, (s0.x + s1.x) + (s2.x + s3.x));
    atomicAdd(dst + 1, (s0.y + s1.y) + (s2.y + s3.y));
    atomicAdd(dst + 2, (s0.z + s1.z) + (s2.z + s3.z));
    atomicAdd(dst + 3, (s0.w + s1.w) + (s2.w + s3.w));
  }
  gbar2(arr, rel, 1u);

  // ---- iters t=1..19
#pragma unroll 1
  for (int t = 1; t < NIT; ++t) {
    const int last = (t == NIT - 1) ? 1 : 0;
    const float* csP = cs + (size_t)(t - 1) * KSLOT * NN;
    float* csN = cs + (size_t)t * KSLOT * NN;

    // Phase 0: scale[col] = max(1 - SCLC/(sqrt(sum_k cs[k][col]) + EPS), 0)
    // Plain loads are safe: gbar2's threadfence-acquire invalidated L2.
    {
      const int col = threadIdx.x * 4;
      float4 a = make_float4(0.f, 0.f, 0.f, 0.f);
#pragma unroll
      for (int k = 0; k < KSLOT; ++k) {
        const float4 v = *(const float4*)(csP + (size_t)k * NN + col);
        a.x += v.x; a.y += v.y; a.z += v.z; a.w += v.w;
      }
      s_scale[col + 0] = fmaxf(1.0f - SCLC / (sqrtf(a.x) + EPSL), 0.0f);
      s_scale[col + 1] = fmaxf(1.0f - SCLC / (sqrtf(a.y) + EPSL), 0.0f);
      s_scale[col + 2] = fmaxf(1.0f - SCLC / (sqrtf(a.z) + EPSL), 0.0f);
      s_scale[col + 3] = fmaxf(1.0f - SCLC / (sqrtf(a.w) + EPSL), 0.0f);
    }
    __syncthreads();

#pragma unroll
    for (int rr = 0; rr < F_RPW; ++rr) {
      const size_t base = (row0 + rr) * NN + (size_t)lane * 4;
      float u[16];
      float sloc = 0.f;
#pragma unroll
      for (int c = 0; c < 4; ++c) {
        const float4 sq4 = *(const float4*)(SQ + base + c * 256);
        const float4 sc4 = *(const float4*)(&s_scale[c * 256 + lane * 4]);
        const float sq[4] = {sq4.x, sq4.y, sq4.z, sq4.w};
        const float sc[4] = {sc4.x, sc4.y, sc4.z, sc4.w};
#pragma unroll
        for (int j = 0; j < 4; ++j) {
          const float vv = V[rr][c * 4 + j];
          const float s = fmaxf(vv - THR, 0.f);   // softthr, V>=0
          const float X = sc[j] * s;              // X_t (never stored)
          const float zz = vv - X;                // Z_t
          const float Xm = (X == 0.f) ? MINV : X;
          const float uu = sq[j] * sqrtf(Xm) * __expf(-0.5f * zz);
          u[c * 4 + j] = uu;
          V[rr][c * 4 + j] = zz;                  // state slot now holds z
          sloc += uu;
        }
      }
      const float inv = 1.0f / wred_sum(sloc);
      if (!last) {
#pragma unroll
        for (int c = 0; c < 4; ++c) {
          float a[4];
#pragma unroll
          for (int j = 0; j < 4; ++j) {
            const float nv = u[c * 4 + j] * inv + V[rr][c * 4 + j];  // R+z
            V[rr][c * 4 + j] = nv;               // V_{t+1}
            const float s = fmaxf(nv - THR, 0.f);
            a[j] = s * s;
          }
          float* sp = &s_part[wv * NN + c * 256 + lane * 4];
          if (rr == 0) {
            *(float4*)sp = make_float4(a[0], a[1], a[2], a[3]);
          } else {
            float4 o = *(float4*)sp;
            *(float4*)sp =
                make_float4(o.x + a[0], o.y + a[1], o.z + a[2], o.w + a[3]);
          }
        }
      } else {
#pragma unroll
        for (int c = 0; c < 4; ++c) {
          *(float4*)(OUT + base + c * 256) =
              make_float4(u[c * 4 + 0] * inv, u[c * 4 + 1] * inv,
                          u[c * 4 + 2] * inv, u[c * 4 + 3] * inv);  // R_20
        }
      }
    }

    if (!last) {
      __syncthreads();
      {
        const int col = threadIdx.x * 4;
        const float4 s0 = *(float4*)(&s_part[0 * NN + col]);
        const float4 s1 = *(float4*)(&s_part[1 * NN + col]);
        const float4 s2 = *(float4*)(&s_part[2 * NN + col]);
        const float4 s3 = *(float4*)(&s_part[3 * NN + col]);
        float* dst = csN + (size_t)(blockIdx.x & (KSLOT - 1)) * NN + col;
        atomicAdd(dst + 0, (s0.x + s1.x) + (s2.x + s3.x));
        atomicAdd(dst + 1, (s0.y + s1.y) + (s2.y + s3.y));
        atomicAdd(dst + 2, (s0.z + s1.z) + (s2.z + s3.z));
        atomicAdd(dst + 3, (s0.w + s1.w) + (s2.w + s3.w));
      }
      gbar2(arr, rel, (unsigned)(t + 1));
    }
  }
}

// ======================= fallback (proven, 1108 µs) ========================
__global__ __launch_bounds__(TPB) void k_start(const float* __restrict__ R0,
                                               float* __restrict__ V,
                                               float* __restrict__ SQ,
                                               float* __restrict__ cs0) {
  __shared__ float s_part[WPB * NN];
  const int lane = threadIdx.x & 63;
  const int wv = threadIdx.x >> 6;
#pragma unroll
  for (int rr = 0; rr < FB_RPW; ++rr) {
    const size_t row = (size_t)blockIdx.x * FB_RPB + wv * FB_RPW + rr;
    const size_t base = row * NN + (size_t)lane * 4;
    float r0v[16];
    float sloc = 0.f;
#pragma unroll
    for (int c = 0; c < 4; ++c) {
      const float4 r4 = *(const float4*)(R0 + base + c * 256);
      r0v[c * 4 + 0] = (r4.x == 0.f) ? MINV : r4.x;
      r0v[c * 4 + 1] = (r4.y == 0.f) ? MINV : r4.y;
      r0v[c * 4 + 2] = (r4.z == 0.f) ? MINV : r4.z;
      r0v[c * 4 + 3] = (r4.w == 0.f) ? MINV : r4.w;
      sloc += (r0v[c * 4 + 0] + r0v[c * 4 + 1]) + (r0v[c * 4 + 2] + r0v[c * 4 + 3]);
      *(float4*)(SQ + base + c * 256) =
          make_float4(sqrtf(r0v[c * 4 + 0]), sqrtf(r0v[c * 4 + 1]),
                      sqrtf(r0v[c * 4 + 2]), sqrtf(r0v[c * 4 + 3]));
    }
    const float inv = 1.0f / wred_sum(sloc);
#pragma unroll
    for (int c = 0; c < 4; ++c) {
      float rn[4], a[4];
#pragma unroll
      for (int j = 0; j < 4; ++j) {
        rn[j] = r0v[c * 4 + j] * inv;
        const float s = softthr_full(rn[j]);
        a[j] = s * s;
      }
      *(float4*)(V + base + c * 256) = make_float4(rn[0], rn[1], rn[2], rn[3]);
      float* sp = &s_part[wv * NN + c * 256 + lane * 4];
      if (rr == 0) {
        *(float4*)sp = make_float4(a[0], a[1], a[2], a[3]);
      } else {
        float4 o = *(float4*)sp;
        *(float4*)sp = make_float4(o.x + a[0], o.y + a[1], o.z + a[2], o.w + a[3]);
      }
    }
  }
  __syncthreads();
  const int col = threadIdx.x * 4;
  const float4 s0 = *(float4*)(&s_part[0 * NN + col]);
  const float4 s1 = *(float4*)(&s_part[1 * NN + col]);
  const float4 s2 = *(float4*)(&s_part[2 * NN + col]);
  const float4 s3 = *(float4*)(&s_part[3 * NN + col]);
  float* dst = cs0 + (size_t)(blockIdx.x & (KSLOT - 1)) * NN + col;
  atomicAdd(dst + 0, (s0.x + s1.x) + (s2.x + s3.x));
  atomicAdd(dst + 1, (s0.y + s1.y) + (s2.y + s3.y));
  atomicAdd(dst + 2, (s0.z + s1.z) + (s2.z + s3.z));
  atomicAdd(dst + 3, (s0.w + s1.w) + (s2.w + s3.w));
}

__global__ __launch_bounds__(TPB) void k_ab(float* __restrict__ V,
                                            const float* __restrict__ SQ,
                                            const float* __restrict__ csPrev,
                                            float* __restrict__ csNext,
                                            int last) {
  __shared__ float s_scale[NN];
  __shared__ float s_part[WPB * NN];
  const int lane = threadIdx.x & 63;
  const int wv = threadIdx.x >> 6;
  {
    const int col = threadIdx.x * 4;
    float4 a = make_float4(0.f, 0.f, 0.f, 0.f);
#pragma unroll
    for (int k = 0; k < KSLOT; ++k) {
      const float4 v = *(const float4*)(csPrev + (size_t)k * NN + col);
      a.x += v.x; a.y += v.y; a.z += v.z; a.w += v.w;
    }
    s_scale[col + 0] = fmaxf(1.0f - SCLC / (sqrtf(a.x) + EPSL), 0.0f);
    s_scale[col + 1] = fmaxf(1.0f - SCLC / (sqrtf(a.y) + EPSL), 0.0f);
    s_scale[col + 2] = fmaxf(1.0f - SCLC / (sqrtf(a.z) + EPSL), 0.0f);
    s_scale[col + 3] = fmaxf(1.0f - SCLC / (sqrtf(a.w) + EPSL), 0.0f);
  }
  __syncthreads();

#pragma unroll
  for (int rr = 0; rr < FB_RPW; ++rr) {
    const size_t row = (size_t)blockIdx.x * FB_RPB + wv * FB_RPW + rr;
    const size_t base = row * NN + (size_t)lane * 4;
    float u[16], z[16];
    float sloc = 0.f;
#pragma unroll
    for (int c = 0; c < 4; ++c) {
      const float4 vv4 = *(const float4*)(V + base + c * 256);
      const float4 sq4 = *(const float4*)(SQ + base + c * 256);
      const float4 sc4 = *(const float4*)(&s_scale[c * 256 + lane * 4]);
      const float vv[4] = {vv4.x, vv4.y, vv4.z, vv4.w};
      const float sq[4] = {sq4.x, sq4.y, sq4.z, sq4.w};
      const float sc[4] = {sc4.x, sc4.y, sc4.z, sc4.w};
#pragma unroll
      for (int j = 0; j < 4; ++j) {
        const float s = softthr_full(vv[j]);
        const float X = sc[j] * s;
        const float zz = vv[j] - X;
        z[c * 4 + j] = zz;
        const float Xm = (X == 0.f) ? MINV : X;
        const float uu = sq[j] * sqrtf(Xm) * __expf(-0.5f * zz);
        u[c * 4 + j] = uu;
        sloc += uu;
      }
    }
    const float inv = 1.0f / wred_sum(sloc);
#pragma unroll
    for (int c = 0; c < 4; ++c) {
      float outv[4];
#pragma unroll
      for (int j = 0; j < 4; ++j) {
        const float rn = u[c * 4 + j] * inv;
        outv[j] = last ? rn : (rn + z[c * 4 + j]);
      }
      *(float4*)(V + base + c * 256) =
          make_float4(outv[0], outv[1], outv[2], outv[3]);
      if (!last) {
        float a[4];
#pragma unroll
        for (int j = 0; j < 4; ++j) {
          const float s = softthr_full(outv[j]);
          a[j] = s * s;
        }
        float* sp = &s_part[wv * NN + c * 256 + lane * 4];
        if (rr == 0) {
          *(float4*)sp = make_float4(a[0], a[1], a[2], a[3]);
        } else {
          float4 o = *(float4*)sp;
          *(float4*)sp =
              make_float4(o.x + a[0], o.y + a[1], o.z + a[2], o.w + a[3]);
        }
      }
    }
  }
  if (!last) {
    __syncthreads();
    const int col = threadIdx.x * 4;
    const float4 s0 = *(float4*)(&s_part[0 * NN + col]);
    const float4 s1 = *(float4*)(&s_part[1 * NN + col]);
    const float4 s2 = *(float4*)(&s_part[2 * NN + col]);
    const float4 s3 = *(float4*)(&s_part[3 * NN + col]);
    float* dst = csNext + (size_t)(blockIdx.x & (KSLOT - 1)) * NN + col;
    atomicAdd(dst + 0, (s0.x + s1.x) + (s2.x + s3.x));
    atomicAdd(dst + 1, (s0.y + s1.y) + (s2.y + s3.y));
    atomicAdd(dst + 2, (s0.z + s1.z) + (s2.z + s3.z));
    atomicAdd(dst + 3, (s0.w + s1.w) + (s2.w + s3.w));
  }
}

extern "C" void kernel_launch(void* const* d_in, const int* in_sizes, int n_in,
                              void* d_out, int out_size, void* d_ws, size_t ws_size,
                              hipStream_t stream) {
  (void)in_sizes; (void)n_in; (void)out_size; (void)ws_size;
  const float* R0 = (const float*)d_in[0];
  float* OUT = (float*)d_out;
  float* SQ = (float*)d_ws;   // 64 MB: sqrt(R0'), iteration-invariant
  float* cs = (float*)((char*)d_ws + (size_t)NROWS * NN * sizeof(float));
  unsigned* arr = (unsigned*)((char*)cs + CS_BYTES);       // counters
  unsigned* rel = arr + NARR * ARR_STRIDE + 64;            // own cacheline

  // Gate on CU count only. Co-residency of 512 blocks is guaranteed by
  // static resources (launch_bounds caps VGPR at 256 -> 2 blocks/CU;
  // LDS 20KB -> 8/CU) whenever the device has >= 256 CUs.
  static int mode = -1;
  if (mode < 0) {
    mode = 0;
    int dev = 0, ncu = 0;
    if (hipGetDevice(&dev) == hipSuccess &&
        hipDeviceGetAttribute(&ncu, hipDeviceAttributeMultiprocessorCount,
                              dev) == hipSuccess) {
      if (2L * (long)ncu >= (long)F_NGRID) mode = 1;
    }
  }

  // zero cs slices + arrival counters + release word
  hipMemsetAsync(cs, 0, CS_BYTES + 8192, stream);
  if (mode == 1) {
    k_fused<<<F_NGRID, TPB, 0, stream>>>(R0, OUT, SQ, cs, arr, rel);
  } else {
    k_start<<<FB_NGRID, TPB, 0, stream>>>(R0, OUT, SQ, cs);
    for (int it = 1; it < NIT; ++it) {
      k_ab<<<FB_NGRID, TPB, 0, stream>>>(OUT, SQ,
                                         cs + (size_t)(it - 1) * KSLOT * NN,
                                         cs + (size_t)it * KSLOT * NN,
                                         (it == NIT - 1) ? 1 : 0);
    }
  }
}

// Round 5
// 883.919 us; speedup vs baseline: 1.2446x; 1.1621x over previous
//
#include <hip/hip_runtime.h>
#include <hip/hip_fp16.h>
#include <math.h>

// Problem: B=16, M=1024, N=1024 fp32; 20 ADMM iterations.
// RHO=1, LAMBD=0.1, ALPHA=0.5 -> threshold = 0.05, scale-const = 0.05.
//
// Fused persistent kernel. V_t in VGPRs; sqrt(R0') in per-block LDS (fp16).
//   X_t = sc_t * softthr(V_t);  Z_t = V_t - X_t
//   R_{t+1} = normalize(sqrt(R0') * sqrt(X_t') * exp(-Z_t/2))
//   V_{t+1} = R_{t+1} + Z_t
// V >= 0 provably holds every iteration, so softthr(x) = fmaxf(x-THR, 0).
//
// R5 changes vs R4 (stall-bound: VALU 31%, 64 MB/iter SQ re-read missing
// L2 (FETCH 661 MB), ~12% V-spill at VGPR_Count=124):
//  - SQ lives in LDS as fp16: 32 rows x 1024 x 2B = 64 KB/block. Zero
//    per-iteration global SQ traffic; global reads shrink to R0 (once) +
//    cs readback (32 KB/block/iter, KSLOT 16->8).
//  - colsum accumulates in regs (csloc[16]; cols identical across a
//    thread's 8 rows), reduced via a 4 KB dual-role LDS buffer (scale
//    broadcast + colsum reduce) -> s_part (16 KB) gone.
//  - 68 KB dynamic LDS via hipFuncSetAttribute, gated; fallback intact.
#define NN 1024
#define NROWS 16384
#define TPB 256           // 4 waves/block
#define WPB 4
#define NIT 20

// fused config: 8 rows/wave -> 32 rows/block -> 512 blocks (2/CU)
#define F_RPW 8
#define F_RPB (WPB * F_RPW)
#define F_NGRID (NROWS / F_RPB)   // 512
#define F_KSLOT 8                 // atomic chain = 512/8 = 64/address
#define F_LDS_BYTES (32 * NN * 2 + NN * 4)  // 64 KB sq_h + 4 KB s_red

// fallback config (proven 1108 us): 2 rows/wave -> 2048 blocks
#define FB_RPW 2
#define FB_RPB (WPB * FB_RPW)
#define FB_NGRID (NROWS / FB_RPB) // 2048
#define KSLOT 16                  // fallback atomic spread

#define MINV 1e-40f
#define THR  0.05f   // ALPHA*LAMBD/RHO
#define SCLC 0.05f   // (1-ALPHA)*LAMBD/RHO
#define EPSL 1e-10f

#define CS_BYTES ((size_t)NIT * KSLOT * NN * sizeof(float))  // max layout
#define NARR 64                   // arrival counters
#define ARR_STRIDE 16             // u32s -> 64 B apart
#define BLKS_PER_ARR (F_NGRID / NARR)  // 8

struct h4 { __half2 a, b; };      // 4 packed fp16

__device__ __forceinline__ float wred_sum(float v) {
#pragma unroll
  for (int o = 32; o > 0; o >>= 1) v += __shfl_xor(v, o, 64);
  return v;
}
__device__ __forceinline__ float softthr_full(float x) {
  return copysignf(fmaxf(fabsf(x) - THR, 0.0f), x);
}

// Two-level grid barrier, generation g = 1,2,3,...
__device__ __forceinline__ void gbar2(unsigned* __restrict__ arr,
                                      unsigned* __restrict__ rel, unsigned g) {
  __syncthreads();
  if (threadIdx.x == 0) {
    __threadfence();  // release my block's cs atomics
    __hip_atomic_fetch_add(&arr[(blockIdx.x & (NARR - 1)) * ARR_STRIDE], 1u,
                           __ATOMIC_RELEASE, __HIP_MEMORY_SCOPE_AGENT);
  }
  if (blockIdx.x == 0) {
    if (threadIdx.x < NARR) {
      const unsigned tgt = (unsigned)BLKS_PER_ARR * g;
      while (__hip_atomic_load(&arr[threadIdx.x * ARR_STRIDE], __ATOMIC_RELAXED,
                               __HIP_MEMORY_SCOPE_AGENT) < tgt)
        __builtin_amdgcn_s_sleep(1);
    }
    __syncthreads();
    if (threadIdx.x == 0) {
      __threadfence();
      __hip_atomic_store(rel, g, __ATOMIC_RELEASE, __HIP_MEMORY_SCOPE_AGENT);
    }
  } else {
    if (threadIdx.x == 0) {
      while (__hip_atomic_load(rel, __ATOMIC_RELAXED,
                               __HIP_MEMORY_SCOPE_AGENT) < g)
        __builtin_amdgcn_s_sleep(2);
      __threadfence();  // acquire side
    }
    __syncthreads();
  }
}

// Reduce csloc[16] across the 4 waves via s_red (4 KB), then one global
// atomicAdd per column into this block's cs slot.
__device__ __forceinline__ void reduce_push(float* __restrict__ s_red,
                                            float (&csloc)[16],
                                            float* __restrict__ dstbase,
                                            int wv, int lane) {
  __syncthreads();  // prior s_red role (scale broadcast) fully consumed
  if (wv == 0) {
#pragma unroll
    for (int c = 0; c < 4; ++c)
      *(float4*)(&s_red[c * 256 + lane * 4]) = make_float4(
          csloc[c * 4 + 0], csloc[c * 4 + 1], csloc[c * 4 + 2], csloc[c * 4 + 3]);
  }
  __syncthreads();
  if (wv != 0) {
#pragma unroll
    for (int c = 0; c < 4; ++c) {
#pragma unroll
      for (int j = 0; j < 4; ++j)
        atomicAdd(&s_red[c * 256 + lane * 4 + j], csloc[c * 4 + j]);
    }
  }
  __syncthreads();
  const int col = (wv * 64 + lane) * 4;
  const float4 v = *(const float4*)(&s_red[col]);
  atomicAdd(dstbase + col + 0, v.x);
  atomicAdd(dstbase + col + 1, v.y);
  atomicAdd(dstbase + col + 2, v.z);
  atomicAdd(dstbase + col + 3, v.w);
}

// ============================ fused kernel =================================
// Layout: row = blockIdx.x*32 + wave*8 + rr; lane L covers cols {c*256+L*4+j}.
__global__ __launch_bounds__(TPB, 2) void k_fused(const float* __restrict__ R0,
                                                  float* __restrict__ OUT,
                                                  float* __restrict__ cs,
                                                  unsigned* __restrict__ arr,
                                                  unsigned* __restrict__ rel) {
  extern __shared__ char smem[];
  __half* sq_h = (__half*)smem;                     // [32][1024] fp16, 64 KB
  float* s_red = (float*)(smem + 32 * NN * 2);      // [1024] f32, 4 KB
  const int lane = threadIdx.x & 63;
  const int wv = threadIdx.x >> 6;
  const int lrow = wv * F_RPW;
  const size_t row0 = (size_t)blockIdx.x * F_RPB + lrow;

  float V[F_RPW][16];   // persistent per-thread state (128 VGPRs)
  float csloc[16];
#pragma unroll
  for (int i = 0; i < 16; ++i) csloc[i] = 0.f;

  // ---- iter 0: V_1 = R0'/rowsum(R0'); sq_h = fp16(sqrt(R0'));
  //      csloc += softthr(V_1)^2.
#pragma unroll
  for (int rr = 0; rr < F_RPW; ++rr) {
    const size_t base = (row0 + rr) * NN + (size_t)lane * 4;
    float sloc = 0.f;
#pragma unroll
    for (int c = 0; c < 4; ++c) {
      const float4 r4 = *(const float4*)(R0 + base + c * 256);
      const float p0 = (r4.x == 0.f) ? MINV : r4.x;
      const float p1 = (r4.y == 0.f) ? MINV : r4.y;
      const float p2 = (r4.z == 0.f) ? MINV : r4.z;
      const float p3 = (r4.w == 0.f) ? MINV : r4.w;
      V[rr][c * 4 + 0] = p0;
      V[rr][c * 4 + 1] = p1;
      V[rr][c * 4 + 2] = p2;
      V[rr][c * 4 + 3] = p3;
      sloc += (p0 + p1) + (p2 + p3);
      h4 hv;
      hv.a = __floats2half2_rn(sqrtf(p0), sqrtf(p1));
      hv.b = __floats2half2_rn(sqrtf(p2), sqrtf(p3));
      *(h4*)(&sq_h[(lrow + rr) * NN + c * 256 + lane * 4]) = hv;
    }
    const float inv = 1.0f / wred_sum(sloc);
#pragma unroll
    for (int c = 0; c < 4; ++c) {
#pragma unroll
      for (int j = 0; j < 4; ++j) {
        const float rn = V[rr][c * 4 + j] * inv;  // V_1 = R_1 (Z_0 = 0)
        V[rr][c * 4 + j] = rn;
        const float s = fmaxf(rn - THR, 0.f);     // V >= 0
        csloc[c * 4 + j] += s * s;
      }
    }
  }
  reduce_push(s_red, csloc, cs + (size_t)(blockIdx.x & (F_KSLOT - 1)) * NN,
              wv, lane);
  gbar2(arr, rel, 1u);

  // ---- iters t=1..19
#pragma unroll 1
  for (int t = 1; t < NIT; ++t) {
    const int last = (t == NIT - 1) ? 1 : 0;
    const float* csP = cs + (size_t)(t - 1) * F_KSLOT * NN;
    float* csN = cs + (size_t)t * F_KSLOT * NN;

    // Phase 0: scale[col] = max(1 - SCLC/(sqrt(sum_k cs[k][col]) + EPS), 0)
    // -> s_red broadcast. (First touch of csP is after the barrier; no
    // stale-cache hazard.)
    {
      const int col = threadIdx.x * 4;
      float4 a = make_float4(0.f, 0.f, 0.f, 0.f);
#pragma unroll
      for (int k = 0; k < F_KSLOT; ++k) {
        const float4 v = *(const float4*)(csP + (size_t)k * NN + col);
        a.x += v.x; a.y += v.y; a.z += v.z; a.w += v.w;
      }
      float4 sc4;
      sc4.x = fmaxf(1.0f - SCLC / (sqrtf(a.x) + EPSL), 0.0f);
      sc4.y = fmaxf(1.0f - SCLC / (sqrtf(a.y) + EPSL), 0.0f);
      sc4.z = fmaxf(1.0f - SCLC / (sqrtf(a.z) + EPSL), 0.0f);
      sc4.w = fmaxf(1.0f - SCLC / (sqrtf(a.w) + EPSL), 0.0f);
      *(float4*)(&s_red[col]) = sc4;
    }
    __syncthreads();

    // hoist this lane's 16 scale values into regs (same cols for all rows)
    float scr[16];
#pragma unroll
    for (int c = 0; c < 4; ++c) {
      const float4 s4 = *(const float4*)(&s_red[c * 256 + lane * 4]);
      scr[c * 4 + 0] = s4.x; scr[c * 4 + 1] = s4.y;
      scr[c * 4 + 2] = s4.z; scr[c * 4 + 3] = s4.w;
    }
#pragma unroll
    for (int i = 0; i < 16; ++i) csloc[i] = 0.f;

#pragma unroll
    for (int rr = 0; rr < F_RPW; ++rr) {
      float u[16];
      float sloc = 0.f;
#pragma unroll
      for (int c = 0; c < 4; ++c) {
        const h4 hv =
            *(const h4*)(&sq_h[(lrow + rr) * NN + c * 256 + lane * 4]);
        const float2 f01 = __half22float2(hv.a);
        const float2 f23 = __half22float2(hv.b);
        const float sqv[4] = {f01.x, f01.y, f23.x, f23.y};
#pragma unroll
        for (int j = 0; j < 4; ++j) {
          const float vv = V[rr][c * 4 + j];
          const float s = fmaxf(vv - THR, 0.f);   // softthr, V>=0
          const float X = scr[c * 4 + j] * s;     // X_t (never stored)
          const float zz = vv - X;                // Z_t
          const float Xm = (X == 0.f) ? MINV : X;
          const float uu = sqv[j] * sqrtf(Xm) * __expf(-0.5f * zz);
          u[c * 4 + j] = uu;
          V[rr][c * 4 + j] = zz;                  // state slot now holds z
          sloc += uu;
        }
      }
      const float inv = 1.0f / wred_sum(sloc);
      if (!last) {
#pragma unroll
        for (int c = 0; c < 4; ++c) {
#pragma unroll
          for (int j = 0; j < 4; ++j) {
            const float nv = u[c * 4 + j] * inv + V[rr][c * 4 + j];  // R+z
            V[rr][c * 4 + j] = nv;               // V_{t+1}
            const float s = fmaxf(nv - THR, 0.f);
            csloc[c * 4 + j] += s * s;
          }
        }
      } else {
        const size_t base = (row0 + rr) * NN + (size_t)lane * 4;
#pragma unroll
        for (int c = 0; c < 4; ++c) {
          *(float4*)(OUT + base + c * 256) =
              make_float4(u[c * 4 + 0] * inv, u[c * 4 + 1] * inv,
                          u[c * 4 + 2] * inv, u[c * 4 + 3] * inv);  // R_20
        }
      }
    }

    if (!last) {
      reduce_push(s_red, csloc,
                  csN + (size_t)(blockIdx.x & (F_KSLOT - 1)) * NN, wv, lane);
      gbar2(arr, rel, (unsigned)(t + 1));
    }
  }
}

// ======================= fallback (proven, 1108 µs) ========================
__global__ __launch_bounds__(TPB) void k_start(const float* __restrict__ R0,
                                               float* __restrict__ V,
                                               float* __restrict__ SQ,
                                               float* __restrict__ cs0) {
  __shared__ float s_part[WPB * NN];
  const int lane = threadIdx.x & 63;
  const int wv = threadIdx.x >> 6;
#pragma unroll
  for (int rr = 0; rr < FB_RPW; ++rr) {
    const size_t row = (size_t)blockIdx.x * FB_RPB + wv * FB_RPW + rr;
    const size_t base = row * NN + (size_t)lane * 4;
    float r0v[16];
    float sloc = 0.f;
#pragma unroll
    for (int c = 0; c < 4; ++c) {
      const float4 r4 = *(const float4*)(R0 + base + c * 256);
      r0v[c * 4 + 0] = (r4.x == 0.f) ? MINV : r4.x;
      r0v[c * 4 + 1] = (r4.y == 0.f) ? MINV : r4.y;
      r0v[c * 4 + 2] = (r4.z == 0.f) ? MINV : r4.z;
      r0v[c * 4 + 3] = (r4.w == 0.f) ? MINV : r4.w;
      sloc += (r0v[c * 4 + 0] + r0v[c * 4 + 1]) + (r0v[c * 4 + 2] + r0v[c * 4 + 3]);
      *(float4*)(SQ + base + c * 256) =
          make_float4(sqrtf(r0v[c * 4 + 0]), sqrtf(r0v[c * 4 + 1]),
                      sqrtf(r0v[c * 4 + 2]), sqrtf(r0v[c * 4 + 3]));
    }
    const float inv = 1.0f / wred_sum(sloc);
#pragma unroll
    for (int c = 0; c < 4; ++c) {
      float rn[4], a[4];
#pragma unroll
      for (int j = 0; j < 4; ++j) {
        rn[j] = r0v[c * 4 + j] * inv;
        const float s = softthr_full(rn[j]);
        a[j] = s * s;
      }
      *(float4*)(V + base + c * 256) = make_float4(rn[0], rn[1], rn[2], rn[3]);
      float* sp = &s_part[wv * NN + c * 256 + lane * 4];
      if (rr == 0) {
        *(float4*)sp = make_float4(a[0], a[1], a[2], a[3]);
      } else {
        float4 o = *(float4*)sp;
        *(float4*)sp = make_float4(o.x + a[0], o.y + a[1], o.z + a[2], o.w + a[3]);
      }
    }
  }
  __syncthreads();
  const int col = threadIdx.x * 4;
  const float4 s0 = *(float4*)(&s_part[0 * NN + col]);
  const float4 s1 = *(float4*)(&s_part[1 * NN + col]);
  const float4 s2 = *(float4*)(&s_part[2 * NN + col]);
  const float4 s3 = *(float4*)(&s_part[3 * NN + col]);
  float* dst = cs0 + (size_t)(blockIdx.x & (KSLOT - 1)) * NN + col;
  atomicAdd(dst + 0, (s0.x + s1.x) + (s2.x + s3.x));
  atomicAdd(dst + 1, (s0.y + s1.y) + (s2.y + s3.y));
  atomicAdd(dst + 2, (s0.z + s1.z) + (s2.z + s3.z));
  atomicAdd(dst + 3, (s0.w + s1.w) + (s2.w + s3.w));
}

__global__ __launch_bounds__(TPB) void k_ab(float* __restrict__ V,
                                            const float* __restrict__ SQ,
                                            const float* __restrict__ csPrev,
                                            float* __restrict__ csNext,
                                            int last) {
  __shared__ float s_scale[NN];
  __shared__ float s_part[WPB * NN];
  const int lane = threadIdx.x & 63;
  const int wv = threadIdx.x >> 6;
  {
    const int col = threadIdx.x * 4;
    float4 a = make_float4(0.f, 0.f, 0.f, 0.f);
#pragma unroll
    for (int k = 0; k < KSLOT; ++k) {
      const float4 v = *(const float4*)(csPrev + (size_t)k * NN + col);
      a.x += v.x; a.y += v.y; a.z += v.z; a.w += v.w;
    }
    s_scale[col + 0] = fmaxf(1.0f - SCLC / (sqrtf(a.x) + EPSL), 0.0f);
    s_scale[col + 1] = fmaxf(1.0f - SCLC / (sqrtf(a.y) + EPSL), 0.0f);
    s_scale[col + 2] = fmaxf(1.0f - SCLC / (sqrtf(a.z) + EPSL), 0.0f);
    s_scale[col + 3] = fmaxf(1.0f - SCLC / (sqrtf(a.w) + EPSL), 0.0f);
  }
  __syncthreads();

#pragma unroll
  for (int rr = 0; rr < FB_RPW; ++rr) {
    const size_t row = (size_t)blockIdx.x * FB_RPB + wv * FB_RPW + rr;
    const size_t base = row * NN + (size_t)lane * 4;
    float u[16], z[16];
    float sloc = 0.f;
#pragma unroll
    for (int c = 0; c < 4; ++c) {
      const float4 vv4 = *(const float4*)(V + base + c * 256);
      const float4 sq4 = *(const float4*)(SQ + base + c * 256);
      const float4 sc4 = *(const float4*)(&s_scale[c * 256 + lane * 4]);
      const float vv[4] = {vv4.x, vv4.y, vv4.z, vv4.w};
      const float sq[4] = {sq4.x, sq4.y, sq4.z, sq4.w};
      const float sc[4] = {sc4.x, sc4.y, sc4.z, sc4.w};
#pragma unroll
      for (int j = 0; j < 4; ++j) {
        const float s = softthr_full(vv[j]);
        const float X = sc[j] * s;
        const float zz = vv[j] - X;
        z[c * 4 + j] = zz;
        const float Xm = (X == 0.f) ? MINV : X;
        const float uu = sq[j] * sqrtf(Xm) * __expf(-0.5f * zz);
        u[c * 4 + j] = uu;
        sloc += uu;
      }
    }
    const float inv = 1.0f / wred_sum(sloc);
#pragma unroll
    for (int c = 0; c < 4; ++c) {
      float outv[4];
#pragma unroll
      for (int j = 0; j < 4; ++j) {
        const float rn = u[c * 4 + j] * inv;
        outv[j] = last ? rn : (rn + z[c * 4 + j]);
      }
      *(float4*)(V + base + c * 256) =
          make_float4(outv[0], outv[1], outv[2], outv[3]);
      if (!last) {
        float a[4];
#pragma unroll
        for (int j = 0; j < 4; ++j) {
          const float s = softthr_full(outv[j]);
          a[j] = s * s;
        }
        float* sp = &s_part[wv * NN + c * 256 + lane * 4];
        if (rr == 0) {
          *(float4*)sp = make_float4(a[0], a[1], a[2], a[3]);
        } else {
          float4 o = *(float4*)sp;
          *(float4*)sp =
              make_float4(o.x + a[0], o.y + a[1], o.z + a[2], o.w + a[3]);
        }
      }
    }
  }
  if (!last) {
    __syncthreads();
    const int col = threadIdx.x * 4;
    const float4 s0 = *(float4*)(&s_part[0 * NN + col]);
    const float4 s1 = *(float4*)(&s_part[1 * NN + col]);
    const float4 s2 = *(float4*)(&s_part[2 * NN + col]);
    const float4 s3 = *(float4*)(&s_part[3 * NN + col]);
    float* dst = csNext + (size_t)(blockIdx.x & (KSLOT - 1)) * NN + col;
    atomicAdd(dst + 0, (s0.x + s1.x) + (s2.x + s3.x));
    atomicAdd(dst + 1, (s0.y + s1.y) + (s2.y + s3.y));
    atomicAdd(dst + 2, (s0.z + s1.z) + (s2.z + s3.z));
    atomicAdd(dst + 3, (s0.w + s1.w) + (s2.w + s3.w));
  }
}

extern "C" void kernel_launch(void* const* d_in, const int* in_sizes, int n_in,
                              void* d_out, int out_size, void* d_ws, size_t ws_size,
                              hipStream_t stream) {
  (void)in_sizes; (void)n_in; (void)out_size; (void)ws_size;
  const float* R0 = (const float*)d_in[0];
  float* OUT = (float*)d_out;
  float* SQ = (float*)d_ws;   // 64 MB: used by fallback only
  float* cs = (float*)((char*)d_ws + (size_t)NROWS * NN * sizeof(float));
  unsigned* arr = (unsigned*)((char*)cs + CS_BYTES);       // counters
  unsigned* rel = arr + NARR * ARR_STRIDE + 64;            // own cacheline

  // Gate: fused mode needs >= 256 CUs (co-residency: launch_bounds caps
  // VGPR at 256 -> 2 blocks/CU; 68 KB LDS -> 2 blocks/CU; 2*256 >= 512)
  // and the dynamic-LDS attribute to take.
  static int mode = -1;
  if (mode < 0) {
    mode = 0;
    int dev = 0, ncu = 0;
    if (hipGetDevice(&dev) == hipSuccess &&
        hipDeviceGetAttribute(&ncu, hipDeviceAttributeMultiprocessorCount,
                              dev) == hipSuccess &&
        2L * (long)ncu >= (long)F_NGRID &&
        hipFuncSetAttribute(reinterpret_cast<const void*>(k_fused),
                            hipFuncAttributeMaxDynamicSharedMemorySize,
                            F_LDS_BYTES) == hipSuccess) {
      mode = 1;
    }
  }

  // zero cs slices + arrival counters + release word
  hipMemsetAsync(cs, 0, CS_BYTES + 8192, stream);
  if (mode == 1) {
    k_fused<<<F_NGRID, TPB, F_LDS_BYTES, stream>>>(R0, OUT, cs, arr, rel);
  } else {
    k_start<<<FB_NGRID, TPB, 0, stream>>>(R0, OUT, SQ, cs);
    for (int it = 1; it < NIT; ++it) {
      k_ab<<<FB_NGRID, TPB, 0, stream>>>(OUT, SQ,
                                         cs + (size_t)(it - 1) * KSLOT * NN,
                                         cs + (size_t)it * KSLOT * NN,
                                         (it == NIT - 1) ? 1 : 0);
    }
  }
}